// Round 9
// baseline (264.994 us; speedup 1.0000x reference)
//
#include <hip/hip_runtime.h>
#include <hip/hip_bf16.h>
#include <cstdint>
#include <cstddef>

// ---------------------------------------------------------------------------
// Self-attention, B=4 S=2048 D=1024. Inputs FLOAT32, output FLOAT32.
//   Q = x@Wq^T+bq ; K = x@Wk^T+bk ; V = x@Wv^T+bv
//   S = Q@K^T ; P = softmax(S)*(1/32) ; O = P@V
// FP16 pipeline (absmax 9.77e-4 vs threshold 1.758e-3).
// Round-21: REVERT round-20's 32x32x16 MFMA (regressed: qkv 66.4 us, bank
//   conflicts 0 -> 6.29M, ~4 extra cyc/ds_read_b128 — the 32x32 read
//   pattern conflicts in a way the per-8-lane bank model doesn't predict;
//   un-modeled mechanism -> revert per methodology). Source = r19 (verified
//   16x16 core everywhere) + INSTRUMENTATION: qkv launched as 3 dispatches
//   (zbase arg, grid 512 each, ~19 us apiece) so the top-5 profile finally
//   surfaces scores/pv/softmax durations — decides whether the ~80 us gap
//   between dispatch-sum (~164 est) and wall total (~240) is slow kernels
//   (attack them) or inter-kernel gaps (cooperative fusion next).
// Keeps: Sc f16 (r16), XOR LDS swizzle (conflicts=0), global_load_lds w16,
//   f16x4 Vt stores, 2-row softmax, 8x8 super-tile XCD decodes.
// Workspace (peak 150,994,944 B):
//   Qp [8192][1024] f16 @ 0     (16 MB)
//   Kp [8192][1024] f16 @ 16M   (16 MB)
//   Vt [4][1024][2048]  @ 32M   (16 MB)  V^T per batch, f16
//   Sc [4][2048][2048]  @ 48M   (32 MB)  f16 scores
//   P  [4][2048][2048]  @ 112M  (32 MB)  f16 probs
//   xh [8192][1024] f16 @ 48M   (16 MB)  aliases Sc (dead after qkv)
//   Wh 3x[1024][1024]   @ 64M   ( 6 MB)  aliases Sc tail (dead after qkv)
// ---------------------------------------------------------------------------

typedef __attribute__((ext_vector_type(8))) _Float16 f16x8;
typedef __attribute__((ext_vector_type(4))) _Float16 f16x4;
typedef __attribute__((ext_vector_type(4))) float f32x4;

#define BM 128
#define BN 128
#define BK 64

#define NBATCH 4
#define SEQ 2048
#define DIM 1024
#define MTOT (NBATCH * SEQ)   // 8192

__device__ __forceinline__ void async_ld16(const void* g, void* l) {
  __builtin_amdgcn_global_load_lds((__attribute__((address_space(1))) void*)(g),
                                   (__attribute__((address_space(3))) void*)(l),
                                   16, 0, 0);
}

// C[m0..+127][n0..+127] += A[m,k] * B[n,k]  (row-major, B^T GEMM)
// A,B f16; async global->LDS staging (XOR-swizzled slots); 4 waves 2x2;
// each wave 64x64 via 4x4 of 16x16x32 f16 MFMA.  (m97-style 2-barrier core,
// measured ~910 TF on qkv — proven; 32x32 variant and phase-splits both
// regressed: r13/r17/r20 evidence. Do not touch.)
__device__ __forceinline__ void gemm_core(const _Float16* __restrict__ A, int lda,
                                          const _Float16* __restrict__ B, int ldb,
                                          int K, int m0, int n0,
                                          _Float16* As, _Float16* Bs,
                                          f32x4 (&acc)[4][4]) {
  const int t = threadIdx.x;
  const int w = t >> 6;
  const int lrow = t & 15;
  const int quad = (t >> 4) & 3;
  const int wm = (w >> 1) << 6;
  const int wn = (w & 1) << 6;

  // Staging: thread t covers tile row rb (+32 per i), global colblock
  // (t&7)^(rb&7) (XOR swizzle; LDS dest is the wave-contiguous slot t&7).
  const int rb = t >> 3;                               // 0..31
  const int co = (((t & 7) ^ (rb & 7)) << 3);          // swizzled source col
  const _Float16* Ap = A + (size_t)(m0 + rb) * lda + co;
  const _Float16* Bp = B + (size_t)(n0 + rb) * ldb + co;

  const int sw = lrow & 7;  // row-phase for read-side swizzle

  for (int k0 = 0; k0 < K; k0 += BK) {
#pragma unroll
    for (int i = 0; i < 4; ++i)
      async_ld16(Ap + (size_t)(i * 32) * lda + k0, As + i * 2048 + (w << 9));
#pragma unroll
    for (int i = 0; i < 4; ++i)
      async_ld16(Bp + (size_t)(i * 32) * ldb + k0, Bs + i * 2048 + (w << 9));
    __syncthreads();
#pragma unroll
    for (int kk = 0; kk < BK; kk += 32) {
      const int slot = ((kk >> 3) + quad) ^ sw;  // swizzled 8-elt slot index
      f16x8 af[4], bfr[4];
#pragma unroll
      for (int mi = 0; mi < 4; ++mi)
        af[mi] = *(const f16x8*)(As + (wm + mi * 16 + lrow) * BK + (slot << 3));
#pragma unroll
      for (int ni = 0; ni < 4; ++ni)
        bfr[ni] = *(const f16x8*)(Bs + (wn + ni * 16 + lrow) * BK + (slot << 3));
#pragma unroll
      for (int mi = 0; mi < 4; ++mi)
#pragma unroll
        for (int ni = 0; ni < 4; ++ni)
          acc[mi][ni] = __builtin_amdgcn_mfma_f32_16x16x32_f16(af[mi], bfr[ni],
                                                              acc[mi][ni], 0, 0, 0);
    }
    __syncthreads();
  }
}

// ---------------------------------------------------------------------------
// Kernel 0: fused f32 -> f16 cast for x, Wq, Wk, Wv.
__global__ __launch_bounds__(256) void split_all_kernel(
    const float* __restrict__ x, const float* __restrict__ Wq,
    const float* __restrict__ Wk, const float* __restrict__ Wv,
    _Float16* __restrict__ xh, _Float16* __restrict__ Wqh,
    _Float16* __restrict__ Wkh, _Float16* __restrict__ Wvh) {
  int r = blockIdx.x;
  const float* src;
  _Float16* dst;
  if (r < MTOT)            { src = x;  dst = xh;  }
  else if (r < MTOT + DIM) { src = Wq; dst = Wqh; r -= MTOT; }
  else if (r < MTOT + 2 * DIM) { src = Wk; dst = Wkh; r -= MTOT + DIM; }
  else                     { src = Wv; dst = Wvh; r -= MTOT + 2 * DIM; }
  const int t = threadIdx.x;
  const float4 v = ((const float4*)(src + (size_t)r * DIM))[t];
  f16x4 hi = {(_Float16)v.x, (_Float16)v.y, (_Float16)v.z, (_Float16)v.w};
  ((f16x4*)(dst + (size_t)r * DIM))[t] = hi;
}

// ---------------------------------------------------------------------------
// Kernel 1: QKV projection slice z (zbase: 0=Q 1=K 2=V), K=1024 (xh @ W^T).
// Grid 512/launch (round-21: 3 launches so scores/pv surface in top-5
// profiling; ~19 us each). Decode within z: m = (l&7) + 8*(l>>6),
// n = (l>>3)&7 (8x8 super-tiles; XCD = l&7 -> one m-row, B L2-resident).
__global__ __launch_bounds__(256, 2) void qkv_kernel(
    const _Float16* __restrict__ xh,
    const _Float16* __restrict__ Wqh, const float* __restrict__ bq,
    const _Float16* __restrict__ Wkh, const float* __restrict__ bk,
    const _Float16* __restrict__ Wvh, const float* __restrict__ bv,
    _Float16* __restrict__ Qp, _Float16* __restrict__ Kp,
    _Float16* __restrict__ Vt, int zbase) {
  __shared__ alignas(16) _Float16 As[BM * BK];
  __shared__ alignas(16) _Float16 Bs[BN * BK];
  f32x4 acc[4][4] = {};
  const int z = zbase;
  const int r9 = blockIdx.x & 511;
  const int m0 = (((r9 & 7) | ((r9 >> 6) << 3))) * BM;
  const int n0 = ((r9 >> 3) & 7) * BN;
  const _Float16* W = (z == 0) ? Wqh : (z == 1) ? Wkh : Wvh;
  const float* bias = (z == 0) ? bq : (z == 1) ? bk : bv;
  gemm_core(xh, DIM, W, DIM, DIM, m0, n0, As, Bs, acc);

  const int t = threadIdx.x, w = t >> 6, lrow = t & 15, quad = (t >> 4) & 3;
  const int wm = (w >> 1) << 6, wn = (w & 1) << 6;
  if (z == 2) {
    // Vt[b][col][s]: 4 consecutive s per (mi,ni) -> vectorized f16x4 store.
    const int b = m0 >> 11;
    const int s_base = (m0 & (SEQ - 1)) + wm + quad * 4;
#pragma unroll
    for (int ni = 0; ni < 4; ++ni) {
      const int col = n0 + wn + ni * 16 + lrow;
      const float bb = bias[col];
      _Float16* vrow = Vt + (size_t)((b << 10) + col) * SEQ;
#pragma unroll
      for (int mi = 0; mi < 4; ++mi) {
        f16x4 v4 = {(_Float16)(acc[mi][ni][0] + bb),
                    (_Float16)(acc[mi][ni][1] + bb),
                    (_Float16)(acc[mi][ni][2] + bb),
                    (_Float16)(acc[mi][ni][3] + bb)};
        *(f16x4*)(vrow + s_base + mi * 16) = v4;
      }
    }
  } else {
    _Float16* base = (z == 0) ? Qp : Kp;
#pragma unroll
    for (int ni = 0; ni < 4; ++ni) {
      const int col = n0 + wn + ni * 16 + lrow;
      const float bb = bias[col];
#pragma unroll
      for (int mi = 0; mi < 4; ++mi) {
#pragma unroll
        for (int r = 0; r < 4; ++r) {
          const int row = m0 + wm + mi * 16 + quad * 4 + r;
          base[(size_t)row * DIM + col] = (_Float16)(acc[mi][ni][r] + bb);
        }
      }
    }
  }
}

// ---------------------------------------------------------------------------
// Kernel 2: scores[b] = Q[b] @ K[b]^T (K=1024), F16 out.
// 1-D grid, 256 blocks/batch: s=r>>6 picks (m_sup=s&1, n_sup=s>>1);
// m=(r&7)+8*m_sup, n=((r>>3)&7)+8*n_sup.
__global__ __launch_bounds__(256, 2) void scores_kernel(
    const _Float16* __restrict__ Qp, const _Float16* __restrict__ Kp,
    _Float16* __restrict__ Sc) {
  __shared__ alignas(16) _Float16 As[BM * BK];
  __shared__ alignas(16) _Float16 Bs[BN * BK];
  f32x4 acc[4][4] = {};
  const int l = blockIdx.x;
  const int b = l >> 8;
  const int r8 = l & 255;
  const int s = r8 >> 6;
  const int m0 = ((r8 & 7) | ((s & 1) << 3)) * BM;
  const int n0 = (((r8 >> 3) & 7) | ((s >> 1) << 3)) * BN;
  gemm_core(Qp + (size_t)b * SEQ * DIM, DIM,
            Kp + (size_t)b * SEQ * DIM, DIM, DIM, m0, n0, As, Bs, acc);
  _Float16* out = Sc + (size_t)b * SEQ * SEQ;
  const int t = threadIdx.x, w = t >> 6, lrow = t & 15, quad = (t >> 4) & 3;
  const int wm = (w >> 1) << 6, wn = (w & 1) << 6;
#pragma unroll
  for (int ni = 0; ni < 4; ++ni) {
    const int col = n0 + wn + ni * 16 + lrow;
#pragma unroll
    for (int mi = 0; mi < 4; ++mi) {
#pragma unroll
      for (int r = 0; r < 4; ++r) {
        const int row = m0 + wm + mi * 16 + quad * 4 + r;
        out[(size_t)row * SEQ + col] = (_Float16)acc[mi][ni][r];
      }
    }
  }
}

// ---------------------------------------------------------------------------
// Kernel 3: row softmax, 2 rows per block (ILP), P = softmax(S)*(1/32), f16.
// Reads f16 Sc (one f16x8 per thread per row), math in f32.
__global__ __launch_bounds__(256) void softmax_kernel(const _Float16* __restrict__ Sc,
                                                      _Float16* __restrict__ P) {
  const int r0 = blockIdx.x * 2;  // rows r0, r0+1
  const _Float16* rowA = Sc + (size_t)r0 * SEQ;
  const _Float16* rowB = rowA + SEQ;
  _Float16* prowA = P + (size_t)r0 * SEQ;
  _Float16* prowB = prowA + SEQ;
  const int t = threadIdx.x;
  const int w = t >> 6;

  const f16x8 ha = ((const f16x8*)rowA)[t];   // cols t*8 .. t*8+7
  const f16x8 hb = ((const f16x8*)rowB)[t];
  float a[8], bb[8];
#pragma unroll
  for (int j = 0; j < 8; ++j) { a[j] = (float)ha[j]; bb[j] = (float)hb[j]; }

  float mA = fmaxf(fmaxf(fmaxf(a[0], a[1]), fmaxf(a[2], a[3])),
                   fmaxf(fmaxf(a[4], a[5]), fmaxf(a[6], a[7])));
  float mB = fmaxf(fmaxf(fmaxf(bb[0], bb[1]), fmaxf(bb[2], bb[3])),
                   fmaxf(fmaxf(bb[4], bb[5]), fmaxf(bb[6], bb[7])));
#pragma unroll
  for (int o = 32; o; o >>= 1) {
    mA = fmaxf(mA, __shfl_down(mA, o));
    mB = fmaxf(mB, __shfl_down(mB, o));
  }
  __shared__ float red[16];
  if ((t & 63) == 0) { red[w] = mA; red[w + 4] = mB; }
  __syncthreads();
  mA = fmaxf(fmaxf(red[0], red[1]), fmaxf(red[2], red[3]));
  mB = fmaxf(fmaxf(red[4], red[5]), fmaxf(red[6], red[7]));

  float eA[8], eB[8];
#pragma unroll
  for (int j = 0; j < 8; ++j) {
    eA[j] = __expf(a[j] - mA);
    eB[j] = __expf(bb[j] - mB);
  }
  float sA = ((eA[0] + eA[1]) + (eA[2] + eA[3])) + ((eA[4] + eA[5]) + (eA[6] + eA[7]));
  float sB = ((eB[0] + eB[1]) + (eB[2] + eB[3])) + ((eB[4] + eB[5]) + (eB[6] + eB[7]));
#pragma unroll
  for (int o = 32; o; o >>= 1) {
    sA += __shfl_down(sA, o);
    sB += __shfl_down(sB, o);
  }
  if ((t & 63) == 0) { red[8 + w] = sA; red[12 + w] = sB; }
  __syncthreads();
  sA = (red[8] + red[9]) + (red[10] + red[11]);
  sB = (red[12] + red[13]) + (red[14] + red[15]);

  const float scA = 0.03125f / sA;  // post-softmax 1/sqrt(Dk)=1/32 folded in
  const float scB = 0.03125f / sB;
  f16x8 oA, oB;
#pragma unroll
  for (int j = 0; j < 8; ++j) {
    oA[j] = (_Float16)(eA[j] * scA);
    oB[j] = (_Float16)(eB[j] * scB);
  }
  ((f16x8*)prowA)[t] = oA;
  ((f16x8*)prowB)[t] = oB;
}

// ---------------------------------------------------------------------------
// Kernel 4: O[b] = P[b] @ V[b]  (Vt [v][s] -> B^T GEMM, K=2048), f32 out.
// 1-D grid, 128 blocks/batch: m=(r&7)+8*(r>>6), n=(r>>3)&7.
__global__ __launch_bounds__(256, 2) void pv_kernel(
    const _Float16* __restrict__ P, const _Float16* __restrict__ Vt,
    float* __restrict__ out) {
  __shared__ alignas(16) _Float16 As[BM * BK];
  __shared__ alignas(16) _Float16 Bs[BN * BK];
  f32x4 acc[4][4] = {};
  const int l = blockIdx.x;
  const int b = l >> 7;
  const int r7 = l & 127;
  const int m0 = ((r7 & 7) | ((r7 >> 6) << 3)) * BM;
  const int n0 = ((r7 >> 3) & 7) * BN;
  gemm_core(P + (size_t)b * SEQ * SEQ, SEQ,
            Vt + (size_t)b * DIM * SEQ, SEQ, SEQ, m0, n0, As, Bs, acc);
  float* ob = out + (size_t)b * SEQ * DIM;
  const int t = threadIdx.x, w = t >> 6, lrow = t & 15, quad = (t >> 4) & 3;
  const int wm = (w >> 1) << 6, wn = (w & 1) << 6;
#pragma unroll
  for (int ni = 0; ni < 4; ++ni) {
    const int col = n0 + wn + ni * 16 + lrow;
#pragma unroll
    for (int mi = 0; mi < 4; ++mi) {
#pragma unroll
      for (int r = 0; r < 4; ++r) {
        const int row = m0 + wm + mi * 16 + quad * 4 + r;
        ob[(size_t)row * DIM + col] = acc[mi][ni][r];
      }
    }
  }
}

// ---------------------------------------------------------------------------
extern "C" void kernel_launch(void* const* d_in, const int* in_sizes, int n_in,
                              void* d_out, int out_size, void* d_ws, size_t ws_size,
                              hipStream_t stream) {
  const float* x  = (const float*)d_in[0];
  const float* Wq = (const float*)d_in[1];
  const float* bq = (const float*)d_in[2];
  const float* Wk = (const float*)d_in[3];
  const float* bk = (const float*)d_in[4];
  const float* Wv = (const float*)d_in[5];
  const float* bv = (const float*)d_in[6];
  float* out = (float*)d_out;  // reference output dtype is float32

  char* ws = (char*)d_ws;
  _Float16* Qp  = (_Float16*)(ws);                 // 16 MB [8192][1024]
  _Float16* Kp  = (_Float16*)(ws + 16777216);      // 16 MB
  _Float16* Vt  = (_Float16*)(ws + 33554432);      // 16 MB [4][1024][2048]
  _Float16* Sc  = (_Float16*)(ws + 50331648);      // 32 MB [4][2048][2048] f16
  _Float16* P   = (_Float16*)(ws + 117440512);     // 32 MB [4][2048][2048] f16
  // xh + W hi planes alias the Sc region (dead once scores_kernel runs).
  _Float16* xh  = (_Float16*)(ws + 50331648);      // 16 MB [8192][1024]
  _Float16* Wqh = (_Float16*)(ws + 67108864);      //  2 MB (dead after qkv)
  _Float16* Wkh = (_Float16*)(ws + 69206016);      //  2 MB (dead after qkv)
  _Float16* Wvh = (_Float16*)(ws + 71303168);      //  2 MB (dead after qkv)
  // peak 150,994,944 B

  dim3 blk(256, 1, 1);
  split_all_kernel<<<dim3(MTOT + 3 * DIM), blk, 0, stream>>>(
      x, Wq, Wk, Wv, xh, Wqh, Wkh, Wvh);
  qkv_kernel<<<dim3(512), blk, 0, stream>>>(
      xh, Wqh, bq, Wkh, bk, Wvh, bv, Qp, Kp, Vt, 0);
  qkv_kernel<<<dim3(512), blk, 0, stream>>>(
      xh, Wqh, bq, Wkh, bk, Wvh, bv, Qp, Kp, Vt, 1);
  qkv_kernel<<<dim3(512), blk, 0, stream>>>(
      xh, Wqh, bq, Wkh, bk, Wvh, bv, Qp, Kp, Vt, 2);
  scores_kernel<<<dim3(NBATCH * 256), blk, 0, stream>>>(Qp, Kp, Sc);
  softmax_kernel<<<dim3(MTOT / 2), blk, 0, stream>>>(Sc, P);
  pv_kernel<<<dim3(NBATCH * 128), blk, 0, stream>>>(P, Vt, out);
}

// Round 10
// 252.706 us; speedup vs baseline: 1.0486x; 1.0486x over previous
//
#include <hip/hip_runtime.h>
#include <hip/hip_bf16.h>
#include <cstdint>
#include <cstddef>

// ---------------------------------------------------------------------------
// Self-attention, B=4 S=2048 D=1024. Inputs FLOAT32, output FLOAT32.
//   Q = x@Wq^T+bq ; K = x@Wk^T+bk ; V = x@Wv^T+bv
//   S = Q@K^T ; P = softmax(S)*(1/32) ; O = P@V
// FP16 pipeline (absmax 9.77e-4 vs threshold 1.758e-3).
// Round-22 delta vs round 21 (265 us; scores profiled 47.2 us, MfmaUtil
//   28.7, FETCH 74 MB): gemm_core -> catalog T3 "minimum 2-phase" double
//   buffer. Old core: stage->sync->compute->sync = tile-k loads drained
//   with ZERO flight (full HBM latency exposed every K-step; the known
//   ~20% m97 stall). New core: stage(next->buf^1) | ds_read+MFMA(cur) |
//   ONE __syncthreads | swap. Loads fly a full compute phase before the
//   drain. Geometry/occupancy preserved (128x128, 4 waves, 64 KB LDS =
//   2 blocks/CU); NO raw barriers / asm vmcnt / phase-locks (r13/r17
//   failures all changed those). qkv back to single fused launch.
// Keeps: Sc f16 (r16), XOR LDS swizzle (conflicts=0), global_load_lds w16,
//   f16x4 Vt stores, 2-row softmax, 8x8 super-tile XCD decodes.
// Workspace (peak 150,994,944 B):
//   Qp [8192][1024] f16 @ 0     (16 MB)
//   Kp [8192][1024] f16 @ 16M   (16 MB)
//   Vt [4][1024][2048]  @ 32M   (16 MB)  V^T per batch, f16
//   Sc [4][2048][2048]  @ 48M   (32 MB)  f16 scores
//   P  [4][2048][2048]  @ 112M  (32 MB)  f16 probs
//   xh [8192][1024] f16 @ 48M   (16 MB)  aliases Sc (dead after qkv)
//   Wh 3x[1024][1024]   @ 64M   ( 6 MB)  aliases Sc tail (dead after qkv)
// ---------------------------------------------------------------------------

typedef __attribute__((ext_vector_type(8))) _Float16 f16x8;
typedef __attribute__((ext_vector_type(4))) _Float16 f16x4;
typedef __attribute__((ext_vector_type(4))) float f32x4;

#define BM 128
#define BN 128
#define BK 64
#define TILE_H (BM * BK)   // 8192 halves = 16 KB per buffer

#define NBATCH 4
#define SEQ 2048
#define DIM 1024
#define MTOT (NBATCH * SEQ)   // 8192

__device__ __forceinline__ void async_ld16(const void* g, void* l) {
  __builtin_amdgcn_global_load_lds((__attribute__((address_space(1))) void*)(g),
                                   (__attribute__((address_space(3))) void*)(l),
                                   16, 0, 0);
}

// Issue one K-tile's staging (8 gload_lds per thread): A 128x64 + B 128x64.
__device__ __forceinline__ void stage_k(const _Float16* __restrict__ Ap, int lda,
                                        const _Float16* __restrict__ Bp, int ldb,
                                        int k0, _Float16* As, _Float16* Bs, int w) {
#pragma unroll
  for (int i = 0; i < 4; ++i)
    async_ld16(Ap + (size_t)(i * 32) * lda + k0, As + i * 2048 + (w << 9));
#pragma unroll
  for (int i = 0; i < 4; ++i)
    async_ld16(Bp + (size_t)(i * 32) * ldb + k0, Bs + i * 2048 + (w << 9));
}

// C[m0..+127][n0..+127] += A[m,k] * B[n,k]  (row-major, B^T GEMM)
// A,B f16; XOR-swizzled async staging; 4 waves 2x2; each wave 64x64 via
// 4x4 of 16x16x32 f16 MFMA. Round-22: double-buffered 2-phase pipeline —
// stage NEXT tile, compute CURRENT, one __syncthreads (vmcnt0+barrier)
// per K-step. As/Bs are [2][TILE_H].
__device__ __forceinline__ void gemm_core(const _Float16* __restrict__ A, int lda,
                                          const _Float16* __restrict__ B, int ldb,
                                          int K, int m0, int n0,
                                          _Float16* As, _Float16* Bs,
                                          f32x4 (&acc)[4][4]) {
  const int t = threadIdx.x;
  const int w = t >> 6;
  const int lrow = t & 15;
  const int quad = (t >> 4) & 3;
  const int wm = (w >> 1) << 6;
  const int wn = (w & 1) << 6;

  // Staging: thread t covers tile row rb (+32 per i), global colblock
  // (t&7)^(rb&7) (XOR swizzle; LDS dest is the wave-contiguous slot t&7).
  const int rb = t >> 3;                               // 0..31
  const int co = (((t & 7) ^ (rb & 7)) << 3);          // swizzled source col
  const _Float16* Ap = A + (size_t)(m0 + rb) * lda + co;
  const _Float16* Bp = B + (size_t)(n0 + rb) * ldb + co;

  const int sw = lrow & 7;  // row-phase for read-side swizzle

  stage_k(Ap, lda, Bp, ldb, 0, As, Bs, w);
  __syncthreads();

  int buf = 0;
  for (int k0 = 0; k0 < K; k0 += BK) {
    const int nxt = k0 + BK;
    if (nxt < K)  // uniform
      stage_k(Ap, lda, Bp, ldb, nxt, As + (buf ^ 1) * TILE_H,
              Bs + (buf ^ 1) * TILE_H, w);
    const _Float16* Ac = As + buf * TILE_H;
    const _Float16* Bc = Bs + buf * TILE_H;
#pragma unroll
    for (int kk = 0; kk < BK; kk += 32) {
      const int slot = ((kk >> 3) + quad) ^ sw;  // swizzled 8-elt slot index
      f16x8 af[4], bfr[4];
#pragma unroll
      for (int mi = 0; mi < 4; ++mi)
        af[mi] = *(const f16x8*)(Ac + (wm + mi * 16 + lrow) * BK + (slot << 3));
#pragma unroll
      for (int ni = 0; ni < 4; ++ni)
        bfr[ni] = *(const f16x8*)(Bc + (wn + ni * 16 + lrow) * BK + (slot << 3));
#pragma unroll
      for (int mi = 0; mi < 4; ++mi)
#pragma unroll
        for (int ni = 0; ni < 4; ++ni)
          acc[mi][ni] = __builtin_amdgcn_mfma_f32_16x16x32_f16(af[mi], bfr[ni],
                                                              acc[mi][ni], 0, 0, 0);
    }
    __syncthreads();  // drains next-tile loads (flew under compute) + read-done
    buf ^= 1;
  }
}

// ---------------------------------------------------------------------------
// Kernel 0: fused f32 -> f16 cast for x, Wq, Wk, Wv.
__global__ __launch_bounds__(256) void split_all_kernel(
    const float* __restrict__ x, const float* __restrict__ Wq,
    const float* __restrict__ Wk, const float* __restrict__ Wv,
    _Float16* __restrict__ xh, _Float16* __restrict__ Wqh,
    _Float16* __restrict__ Wkh, _Float16* __restrict__ Wvh) {
  int r = blockIdx.x;
  const float* src;
  _Float16* dst;
  if (r < MTOT)            { src = x;  dst = xh;  }
  else if (r < MTOT + DIM) { src = Wq; dst = Wqh; r -= MTOT; }
  else if (r < MTOT + 2 * DIM) { src = Wk; dst = Wkh; r -= MTOT + DIM; }
  else                     { src = Wv; dst = Wvh; r -= MTOT + 2 * DIM; }
  const int t = threadIdx.x;
  const float4 v = ((const float4*)(src + (size_t)r * DIM))[t];
  f16x4 hi = {(_Float16)v.x, (_Float16)v.y, (_Float16)v.z, (_Float16)v.w};
  ((f16x4*)(dst + (size_t)r * DIM))[t] = hi;
}

// ---------------------------------------------------------------------------
// Kernel 1: QKV projections, all K=1024 (xh @ Wh^T). 1-D grid, 512 blocks/z.
// Decode: z = l>>9; within z: m = (l&7) + 8*(l>>6), n = (l>>3)&7  (8x8
// super-tiles; XCD = l&7 handles one m-row, B-tiles L2-resident).
__global__ __launch_bounds__(256, 2) void qkv_kernel(
    const _Float16* __restrict__ xh,
    const _Float16* __restrict__ Wqh, const float* __restrict__ bq,
    const _Float16* __restrict__ Wkh, const float* __restrict__ bk,
    const _Float16* __restrict__ Wvh, const float* __restrict__ bv,
    _Float16* __restrict__ Qp, _Float16* __restrict__ Kp,
    _Float16* __restrict__ Vt) {
  __shared__ alignas(16) _Float16 As[2 * TILE_H];
  __shared__ alignas(16) _Float16 Bs[2 * TILE_H];
  f32x4 acc[4][4] = {};
  const int l = blockIdx.x;
  const int z = l >> 9;
  const int r9 = l & 511;
  const int m0 = (((r9 & 7) | ((r9 >> 6) << 3))) * BM;
  const int n0 = ((r9 >> 3) & 7) * BN;
  const _Float16* W = (z == 0) ? Wqh : (z == 1) ? Wkh : Wvh;
  const float* bias = (z == 0) ? bq : (z == 1) ? bk : bv;
  gemm_core(xh, DIM, W, DIM, DIM, m0, n0, As, Bs, acc);

  const int t = threadIdx.x, w = t >> 6, lrow = t & 15, quad = (t >> 4) & 3;
  const int wm = (w >> 1) << 6, wn = (w & 1) << 6;
  if (z == 2) {
    // Vt[b][col][s]: 4 consecutive s per (mi,ni) -> vectorized f16x4 store.
    const int b = m0 >> 11;
    const int s_base = (m0 & (SEQ - 1)) + wm + quad * 4;
#pragma unroll
    for (int ni = 0; ni < 4; ++ni) {
      const int col = n0 + wn + ni * 16 + lrow;
      const float bb = bias[col];
      _Float16* vrow = Vt + (size_t)((b << 10) + col) * SEQ;
#pragma unroll
      for (int mi = 0; mi < 4; ++mi) {
        f16x4 v4 = {(_Float16)(acc[mi][ni][0] + bb),
                    (_Float16)(acc[mi][ni][1] + bb),
                    (_Float16)(acc[mi][ni][2] + bb),
                    (_Float16)(acc[mi][ni][3] + bb)};
        *(f16x4*)(vrow + s_base + mi * 16) = v4;
      }
    }
  } else {
    _Float16* base = (z == 0) ? Qp : Kp;
#pragma unroll
    for (int ni = 0; ni < 4; ++ni) {
      const int col = n0 + wn + ni * 16 + lrow;
      const float bb = bias[col];
#pragma unroll
      for (int mi = 0; mi < 4; ++mi) {
#pragma unroll
        for (int r = 0; r < 4; ++r) {
          const int row = m0 + wm + mi * 16 + quad * 4 + r;
          base[(size_t)row * DIM + col] = (_Float16)(acc[mi][ni][r] + bb);
        }
      }
    }
  }
}

// ---------------------------------------------------------------------------
// Kernel 2: scores[b] = Q[b] @ K[b]^T (K=1024), F16 out.
// 1-D grid, 256 blocks/batch: s=r>>6 picks (m_sup=s&1, n_sup=s>>1);
// m=(r&7)+8*m_sup, n=((r>>3)&7)+8*n_sup.
__global__ __launch_bounds__(256, 2) void scores_kernel(
    const _Float16* __restrict__ Qp, const _Float16* __restrict__ Kp,
    _Float16* __restrict__ Sc) {
  __shared__ alignas(16) _Float16 As[2 * TILE_H];
  __shared__ alignas(16) _Float16 Bs[2 * TILE_H];
  f32x4 acc[4][4] = {};
  const int l = blockIdx.x;
  const int b = l >> 8;
  const int r8 = l & 255;
  const int s = r8 >> 6;
  const int m0 = ((r8 & 7) | ((s & 1) << 3)) * BM;
  const int n0 = (((r8 >> 3) & 7) | ((s >> 1) << 3)) * BN;
  gemm_core(Qp + (size_t)b * SEQ * DIM, DIM,
            Kp + (size_t)b * SEQ * DIM, DIM, DIM, m0, n0, As, Bs, acc);
  _Float16* out = Sc + (size_t)b * SEQ * SEQ;
  const int t = threadIdx.x, w = t >> 6, lrow = t & 15, quad = (t >> 4) & 3;
  const int wm = (w >> 1) << 6, wn = (w & 1) << 6;
#pragma unroll
  for (int ni = 0; ni < 4; ++ni) {
    const int col = n0 + wn + ni * 16 + lrow;
#pragma unroll
    for (int mi = 0; mi < 4; ++mi) {
#pragma unroll
      for (int r = 0; r < 4; ++r) {
        const int row = m0 + wm + mi * 16 + quad * 4 + r;
        out[(size_t)row * SEQ + col] = (_Float16)acc[mi][ni][r];
      }
    }
  }
}

// ---------------------------------------------------------------------------
// Kernel 3: row softmax, 2 rows per block (ILP), P = softmax(S)*(1/32), f16.
// Reads f16 Sc (one f16x8 per thread per row), math in f32.
__global__ __launch_bounds__(256) void softmax_kernel(const _Float16* __restrict__ Sc,
                                                      _Float16* __restrict__ P) {
  const int r0 = blockIdx.x * 2;  // rows r0, r0+1
  const _Float16* rowA = Sc + (size_t)r0 * SEQ;
  const _Float16* rowB = rowA + SEQ;
  _Float16* prowA = P + (size_t)r0 * SEQ;
  _Float16* prowB = prowA + SEQ;
  const int t = threadIdx.x;
  const int w = t >> 6;

  const f16x8 ha = ((const f16x8*)rowA)[t];   // cols t*8 .. t*8+7
  const f16x8 hb = ((const f16x8*)rowB)[t];
  float a[8], bb[8];
#pragma unroll
  for (int j = 0; j < 8; ++j) { a[j] = (float)ha[j]; bb[j] = (float)hb[j]; }

  float mA = fmaxf(fmaxf(fmaxf(a[0], a[1]), fmaxf(a[2], a[3])),
                   fmaxf(fmaxf(a[4], a[5]), fmaxf(a[6], a[7])));
  float mB = fmaxf(fmaxf(fmaxf(bb[0], bb[1]), fmaxf(bb[2], bb[3])),
                   fmaxf(fmaxf(bb[4], bb[5]), fmaxf(bb[6], bb[7])));
#pragma unroll
  for (int o = 32; o; o >>= 1) {
    mA = fmaxf(mA, __shfl_down(mA, o));
    mB = fmaxf(mB, __shfl_down(mB, o));
  }
  __shared__ float red[16];
  if ((t & 63) == 0) { red[w] = mA; red[w + 4] = mB; }
  __syncthreads();
  mA = fmaxf(fmaxf(red[0], red[1]), fmaxf(red[2], red[3]));
  mB = fmaxf(fmaxf(red[4], red[5]), fmaxf(red[6], red[7]));

  float eA[8], eB[8];
#pragma unroll
  for (int j = 0; j < 8; ++j) {
    eA[j] = __expf(a[j] - mA);
    eB[j] = __expf(bb[j] - mB);
  }
  float sA = ((eA[0] + eA[1]) + (eA[2] + eA[3])) + ((eA[4] + eA[5]) + (eA[6] + eA[7]));
  float sB = ((eB[0] + eB[1]) + (eB[2] + eB[3])) + ((eB[4] + eB[5]) + (eB[6] + eB[7]));
#pragma unroll
  for (int o = 32; o; o >>= 1) {
    sA += __shfl_down(sA, o);
    sB += __shfl_down(sB, o);
  }
  if ((t & 63) == 0) { red[8 + w] = sA; red[12 + w] = sB; }
  __syncthreads();
  sA = (red[8] + red[9]) + (red[10] + red[11]);
  sB = (red[12] + red[13]) + (red[14] + red[15]);

  const float scA = 0.03125f / sA;  // post-softmax 1/sqrt(Dk)=1/32 folded in
  const float scB = 0.03125f / sB;
  f16x8 oA, oB;
#pragma unroll
  for (int j = 0; j < 8; ++j) {
    oA[j] = (_Float16)(eA[j] * scA);
    oB[j] = (_Float16)(eB[j] * scB);
  }
  ((f16x8*)prowA)[t] = oA;
  ((f16x8*)prowB)[t] = oB;
}

// ---------------------------------------------------------------------------
// Kernel 4: O[b] = P[b] @ V[b]  (Vt [v][s] -> B^T GEMM, K=2048), f32 out.
// 1-D grid, 128 blocks/batch: m=(r&7)+8*(r>>6), n=(r>>3)&7.
__global__ __launch_bounds__(256, 2) void pv_kernel(
    const _Float16* __restrict__ P, const _Float16* __restrict__ Vt,
    float* __restrict__ out) {
  __shared__ alignas(16) _Float16 As[2 * TILE_H];
  __shared__ alignas(16) _Float16 Bs[2 * TILE_H];
  f32x4 acc[4][4] = {};
  const int l = blockIdx.x;
  const int b = l >> 7;
  const int r7 = l & 127;
  const int m0 = ((r7 & 7) | ((r7 >> 6) << 3)) * BM;
  const int n0 = ((r7 >> 3) & 7) * BN;
  gemm_core(P + (size_t)b * SEQ * SEQ, SEQ,
            Vt + (size_t)b * DIM * SEQ, SEQ, SEQ, m0, n0, As, Bs, acc);
  float* ob = out + (size_t)b * SEQ * DIM;
  const int t = threadIdx.x, w = t >> 6, lrow = t & 15, quad = (t >> 4) & 3;
  const int wm = (w >> 1) << 6, wn = (w & 1) << 6;
#pragma unroll
  for (int ni = 0; ni < 4; ++ni) {
    const int col = n0 + wn + ni * 16 + lrow;
#pragma unroll
    for (int mi = 0; mi < 4; ++mi) {
#pragma unroll
      for (int r = 0; r < 4; ++r) {
        const int row = m0 + wm + mi * 16 + quad * 4 + r;
        ob[(size_t)row * DIM + col] = acc[mi][ni][r];
      }
    }
  }
}

// ---------------------------------------------------------------------------
extern "C" void kernel_launch(void* const* d_in, const int* in_sizes, int n_in,
                              void* d_out, int out_size, void* d_ws, size_t ws_size,
                              hipStream_t stream) {
  const float* x  = (const float*)d_in[0];
  const float* Wq = (const float*)d_in[1];
  const float* bq = (const float*)d_in[2];
  const float* Wk = (const float*)d_in[3];
  const float* bk = (const float*)d_in[4];
  const float* Wv = (const float*)d_in[5];
  const float* bv = (const float*)d_in[6];
  float* out = (float*)d_out;  // reference output dtype is float32

  char* ws = (char*)d_ws;
  _Float16* Qp  = (_Float16*)(ws);                 // 16 MB [8192][1024]
  _Float16* Kp  = (_Float16*)(ws + 16777216);      // 16 MB
  _Float16* Vt  = (_Float16*)(ws + 33554432);      // 16 MB [4][1024][2048]
  _Float16* Sc  = (_Float16*)(ws + 50331648);      // 32 MB [4][2048][2048] f16
  _Float16* P   = (_Float16*)(ws + 117440512);     // 32 MB [4][2048][2048] f16
  // xh + W hi planes alias the Sc region (dead once scores_kernel runs).
  _Float16* xh  = (_Float16*)(ws + 50331648);      // 16 MB [8192][1024]
  _Float16* Wqh = (_Float16*)(ws + 67108864);      //  2 MB (dead after qkv)
  _Float16* Wkh = (_Float16*)(ws + 69206016);      //  2 MB (dead after qkv)
  _Float16* Wvh = (_Float16*)(ws + 71303168);      //  2 MB (dead after qkv)
  // peak 150,994,944 B

  dim3 blk(256, 1, 1);
  split_all_kernel<<<dim3(MTOT + 3 * DIM), blk, 0, stream>>>(
      x, Wq, Wk, Wv, xh, Wqh, Wkh, Wvh);
  qkv_kernel<<<dim3(3 * 512), blk, 0, stream>>>(
      xh, Wqh, bq, Wkh, bk, Wvh, bv, Qp, Kp, Vt);
  scores_kernel<<<dim3(NBATCH * 256), blk, 0, stream>>>(Qp, Kp, Sc);
  softmax_kernel<<<dim3(MTOT / 2), blk, 0, stream>>>(Sc, P);
  pv_kernel<<<dim3(NBATCH * 128), blk, 0, stream>>>(P, Vt, out);
}

// Round 11
// 231.978 us; speedup vs baseline: 1.1423x; 1.0894x over previous
//
#include <hip/hip_runtime.h>
#include <hip/hip_bf16.h>
#include <cstdint>
#include <cstddef>

// ---------------------------------------------------------------------------
// Self-attention, B=4 S=2048 D=1024. Inputs FLOAT32, output FLOAT32.
//   Q = x@Wq^T+bq ; K = x@Wk^T+bk ; V = x@Wv^T+bv
//   S = Q@K^T ; P = softmax(S)*(1/32) ; O = P@V
// FP16 pipeline (absmax 9.77e-4 vs threshold 1.758e-3).
// Round-23: REVERT to round-19 exact (best verified config). Round-22's
//   2-phase dbuf regressed (qkv 75.8 us, MfmaUtil 27.8, Occupancy 19.8 —
//   m132's 64KB-LDS occupancy cut reproduced; the 2-barrier core's hiding
//   comes from inter-block TLP, m114, which dbuf cannibalized).
// Session ledger (10 rounds): r13 coarse 3-buf pipeline -27%; r17 fine
//   4-phase -4%; r20 32x32 MFMA -17% (6.3M bank conflicts); r22 dbuf -34%
//   on qkv. The 2-barrier 128x128 core at ~906 TF IS the m97-structure
//   ceiling (m103: 912); qkv/scores/pv all run 73-91% of it. Remaining
//   documented lever (m201 8-phase + st_16x32 + counted vmcnt) failed
//   twice in reconstruction-from-prose -> hold the verified config.
// Keeps: Sc f16 (r16), XOR LDS swizzle (conflicts=0), global_load_lds w16,
//   K=1024 hi-plane GEMMs, f16x4 Vt stores, 2-row softmax, 8x8 super-tile
//   XCD-aware block decode on qkv/scores/pv.
// Workspace (peak 150,994,944 B):
//   Qp [8192][1024] f16 @ 0     (16 MB)
//   Kp [8192][1024] f16 @ 16M   (16 MB)
//   Vt [4][1024][2048]  @ 32M   (16 MB)  V^T per batch, f16
//   Sc [4][2048][2048]  @ 48M   (32 MB)  f16 scores
//   P  [4][2048][2048]  @ 112M  (32 MB)  f16 probs
//   xh [8192][1024] f16 @ 48M   (16 MB)  aliases Sc (dead after qkv)
//   Wh 3x[1024][1024]   @ 64M   ( 6 MB)  aliases Sc tail (dead after qkv)
// ---------------------------------------------------------------------------

typedef __attribute__((ext_vector_type(8))) _Float16 f16x8;
typedef __attribute__((ext_vector_type(4))) _Float16 f16x4;
typedef __attribute__((ext_vector_type(4))) float f32x4;

#define BM 128
#define BN 128
#define BK 64

#define NBATCH 4
#define SEQ 2048
#define DIM 1024
#define MTOT (NBATCH * SEQ)   // 8192

__device__ __forceinline__ void async_ld16(const void* g, void* l) {
  __builtin_amdgcn_global_load_lds((__attribute__((address_space(1))) void*)(g),
                                   (__attribute__((address_space(3))) void*)(l),
                                   16, 0, 0);
}

// C[m0..+127][n0..+127] += A[m,k] * B[n,k]  (row-major, B^T GEMM)
// A,B f16; async global->LDS staging (XOR-swizzled slots); 4 waves 2x2;
// each wave 64x64 via 4x4 of 16x16x32 f16 MFMA.  (m97-style 2-barrier core,
// measured ~906 TF on qkv — proven ceiling for this structure. Do not
// phase-split (r13/r17), do not 32x32 (r20), do not dbuf (r22).)
__device__ __forceinline__ void gemm_core(const _Float16* __restrict__ A, int lda,
                                          const _Float16* __restrict__ B, int ldb,
                                          int K, int m0, int n0,
                                          _Float16* As, _Float16* Bs,
                                          f32x4 (&acc)[4][4]) {
  const int t = threadIdx.x;
  const int w = t >> 6;
  const int lrow = t & 15;
  const int quad = (t >> 4) & 3;
  const int wm = (w >> 1) << 6;
  const int wn = (w & 1) << 6;

  // Staging: thread t covers tile row rb (+32 per i), global colblock
  // (t&7)^(rb&7) (XOR swizzle; LDS dest is the wave-contiguous slot t&7).
  const int rb = t >> 3;                               // 0..31
  const int co = (((t & 7) ^ (rb & 7)) << 3);          // swizzled source col
  const _Float16* Ap = A + (size_t)(m0 + rb) * lda + co;
  const _Float16* Bp = B + (size_t)(n0 + rb) * ldb + co;

  const int sw = lrow & 7;  // row-phase for read-side swizzle

  for (int k0 = 0; k0 < K; k0 += BK) {
#pragma unroll
    for (int i = 0; i < 4; ++i)
      async_ld16(Ap + (size_t)(i * 32) * lda + k0, As + i * 2048 + (w << 9));
#pragma unroll
    for (int i = 0; i < 4; ++i)
      async_ld16(Bp + (size_t)(i * 32) * ldb + k0, Bs + i * 2048 + (w << 9));
    __syncthreads();
#pragma unroll
    for (int kk = 0; kk < BK; kk += 32) {
      const int slot = ((kk >> 3) + quad) ^ sw;  // swizzled 8-elt slot index
      f16x8 af[4], bfr[4];
#pragma unroll
      for (int mi = 0; mi < 4; ++mi)
        af[mi] = *(const f16x8*)(As + (wm + mi * 16 + lrow) * BK + (slot << 3));
#pragma unroll
      for (int ni = 0; ni < 4; ++ni)
        bfr[ni] = *(const f16x8*)(Bs + (wn + ni * 16 + lrow) * BK + (slot << 3));
#pragma unroll
      for (int mi = 0; mi < 4; ++mi)
#pragma unroll
        for (int ni = 0; ni < 4; ++ni)
          acc[mi][ni] = __builtin_amdgcn_mfma_f32_16x16x32_f16(af[mi], bfr[ni],
                                                              acc[mi][ni], 0, 0, 0);
    }
    __syncthreads();
  }
}

// ---------------------------------------------------------------------------
// Kernel 0: fused f32 -> f16 cast for x, Wq, Wk, Wv.
__global__ __launch_bounds__(256) void split_all_kernel(
    const float* __restrict__ x, const float* __restrict__ Wq,
    const float* __restrict__ Wk, const float* __restrict__ Wv,
    _Float16* __restrict__ xh, _Float16* __restrict__ Wqh,
    _Float16* __restrict__ Wkh, _Float16* __restrict__ Wvh) {
  int r = blockIdx.x;
  const float* src;
  _Float16* dst;
  if (r < MTOT)            { src = x;  dst = xh;  }
  else if (r < MTOT + DIM) { src = Wq; dst = Wqh; r -= MTOT; }
  else if (r < MTOT + 2 * DIM) { src = Wk; dst = Wkh; r -= MTOT + DIM; }
  else                     { src = Wv; dst = Wvh; r -= MTOT + 2 * DIM; }
  const int t = threadIdx.x;
  const float4 v = ((const float4*)(src + (size_t)r * DIM))[t];
  f16x4 hi = {(_Float16)v.x, (_Float16)v.y, (_Float16)v.z, (_Float16)v.w};
  ((f16x4*)(dst + (size_t)r * DIM))[t] = hi;
}

// ---------------------------------------------------------------------------
// Kernel 1: QKV projections, all K=1024 (xh @ Wh^T). 1-D grid, 512 blocks/z.
// Decode: z = l>>9; within z: m = (l&7) + 8*(l>>6), n = (l>>3)&7  (8x8
// super-tiles; XCD = l&7 handles one m-row, B-tiles L2-resident).
__global__ __launch_bounds__(256, 2) void qkv_kernel(
    const _Float16* __restrict__ xh,
    const _Float16* __restrict__ Wqh, const float* __restrict__ bq,
    const _Float16* __restrict__ Wkh, const float* __restrict__ bk,
    const _Float16* __restrict__ Wvh, const float* __restrict__ bv,
    _Float16* __restrict__ Qp, _Float16* __restrict__ Kp,
    _Float16* __restrict__ Vt) {
  __shared__ alignas(16) _Float16 As[BM * BK];
  __shared__ alignas(16) _Float16 Bs[BN * BK];
  f32x4 acc[4][4] = {};
  const int l = blockIdx.x;
  const int z = l >> 9;
  const int r9 = l & 511;
  const int m0 = (((r9 & 7) | ((r9 >> 6) << 3))) * BM;
  const int n0 = ((r9 >> 3) & 7) * BN;
  const _Float16* W = (z == 0) ? Wqh : (z == 1) ? Wkh : Wvh;
  const float* bias = (z == 0) ? bq : (z == 1) ? bk : bv;
  gemm_core(xh, DIM, W, DIM, DIM, m0, n0, As, Bs, acc);

  const int t = threadIdx.x, w = t >> 6, lrow = t & 15, quad = (t >> 4) & 3;
  const int wm = (w >> 1) << 6, wn = (w & 1) << 6;
  if (z == 2) {
    // Vt[b][col][s]: 4 consecutive s per (mi,ni) -> vectorized f16x4 store.
    const int b = m0 >> 11;
    const int s_base = (m0 & (SEQ - 1)) + wm + quad * 4;
#pragma unroll
    for (int ni = 0; ni < 4; ++ni) {
      const int col = n0 + wn + ni * 16 + lrow;
      const float bb = bias[col];
      _Float16* vrow = Vt + (size_t)((b << 10) + col) * SEQ;
#pragma unroll
      for (int mi = 0; mi < 4; ++mi) {
        f16x4 v4 = {(_Float16)(acc[mi][ni][0] + bb),
                    (_Float16)(acc[mi][ni][1] + bb),
                    (_Float16)(acc[mi][ni][2] + bb),
                    (_Float16)(acc[mi][ni][3] + bb)};
        *(f16x4*)(vrow + s_base + mi * 16) = v4;
      }
    }
  } else {
    _Float16* base = (z == 0) ? Qp : Kp;
#pragma unroll
    for (int ni = 0; ni < 4; ++ni) {
      const int col = n0 + wn + ni * 16 + lrow;
      const float bb = bias[col];
#pragma unroll
      for (int mi = 0; mi < 4; ++mi) {
#pragma unroll
        for (int r = 0; r < 4; ++r) {
          const int row = m0 + wm + mi * 16 + quad * 4 + r;
          base[(size_t)row * DIM + col] = (_Float16)(acc[mi][ni][r] + bb);
        }
      }
    }
  }
}

// ---------------------------------------------------------------------------
// Kernel 2: scores[b] = Q[b] @ K[b]^T (K=1024), F16 out.
// 1-D grid, 256 blocks/batch: s=r>>6 picks (m_sup=s&1, n_sup=s>>1);
// m=(r&7)+8*m_sup, n=((r>>3)&7)+8*n_sup.
__global__ __launch_bounds__(256, 2) void scores_kernel(
    const _Float16* __restrict__ Qp, const _Float16* __restrict__ Kp,
    _Float16* __restrict__ Sc) {
  __shared__ alignas(16) _Float16 As[BM * BK];
  __shared__ alignas(16) _Float16 Bs[BN * BK];
  f32x4 acc[4][4] = {};
  const int l = blockIdx.x;
  const int b = l >> 8;
  const int r8 = l & 255;
  const int s = r8 >> 6;
  const int m0 = ((r8 & 7) | ((s & 1) << 3)) * BM;
  const int n0 = (((r8 >> 3) & 7) | ((s >> 1) << 3)) * BN;
  gemm_core(Qp + (size_t)b * SEQ * DIM, DIM,
            Kp + (size_t)b * SEQ * DIM, DIM, DIM, m0, n0, As, Bs, acc);
  _Float16* out = Sc + (size_t)b * SEQ * SEQ;
  const int t = threadIdx.x, w = t >> 6, lrow = t & 15, quad = (t >> 4) & 3;
  const int wm = (w >> 1) << 6, wn = (w & 1) << 6;
#pragma unroll
  for (int ni = 0; ni < 4; ++ni) {
    const int col = n0 + wn + ni * 16 + lrow;
#pragma unroll
    for (int mi = 0; mi < 4; ++mi) {
#pragma unroll
      for (int r = 0; r < 4; ++r) {
        const int row = m0 + wm + mi * 16 + quad * 4 + r;
        out[(size_t)row * SEQ + col] = (_Float16)acc[mi][ni][r];
      }
    }
  }
}

// ---------------------------------------------------------------------------
// Kernel 3: row softmax, 2 rows per block (ILP), P = softmax(S)*(1/32), f16.
// Reads f16 Sc (one f16x8 per thread per row), math in f32.
__global__ __launch_bounds__(256) void softmax_kernel(const _Float16* __restrict__ Sc,
                                                      _Float16* __restrict__ P) {
  const int r0 = blockIdx.x * 2;  // rows r0, r0+1
  const _Float16* rowA = Sc + (size_t)r0 * SEQ;
  const _Float16* rowB = rowA + SEQ;
  _Float16* prowA = P + (size_t)r0 * SEQ;
  _Float16* prowB = prowA + SEQ;
  const int t = threadIdx.x;
  const int w = t >> 6;

  const f16x8 ha = ((const f16x8*)rowA)[t];   // cols t*8 .. t*8+7
  const f16x8 hb = ((const f16x8*)rowB)[t];
  float a[8], bb[8];
#pragma unroll
  for (int j = 0; j < 8; ++j) { a[j] = (float)ha[j]; bb[j] = (float)hb[j]; }

  float mA = fmaxf(fmaxf(fmaxf(a[0], a[1]), fmaxf(a[2], a[3])),
                   fmaxf(fmaxf(a[4], a[5]), fmaxf(a[6], a[7])));
  float mB = fmaxf(fmaxf(fmaxf(bb[0], bb[1]), fmaxf(bb[2], bb[3])),
                   fmaxf(fmaxf(bb[4], bb[5]), fmaxf(bb[6], bb[7])));
#pragma unroll
  for (int o = 32; o; o >>= 1) {
    mA = fmaxf(mA, __shfl_down(mA, o));
    mB = fmaxf(mB, __shfl_down(mB, o));
  }
  __shared__ float red[16];
  if ((t & 63) == 0) { red[w] = mA; red[w + 4] = mB; }
  __syncthreads();
  mA = fmaxf(fmaxf(red[0], red[1]), fmaxf(red[2], red[3]));
  mB = fmaxf(fmaxf(red[4], red[5]), fmaxf(red[6], red[7]));

  float eA[8], eB[8];
#pragma unroll
  for (int j = 0; j < 8; ++j) {
    eA[j] = __expf(a[j] - mA);
    eB[j] = __expf(bb[j] - mB);
  }
  float sA = ((eA[0] + eA[1]) + (eA[2] + eA[3])) + ((eA[4] + eA[5]) + (eA[6] + eA[7]));
  float sB = ((eB[0] + eB[1]) + (eB[2] + eB[3])) + ((eB[4] + eB[5]) + (eB[6] + eB[7]));
#pragma unroll
  for (int o = 32; o; o >>= 1) {
    sA += __shfl_down(sA, o);
    sB += __shfl_down(sB, o);
  }
  if ((t & 63) == 0) { red[8 + w] = sA; red[12 + w] = sB; }
  __syncthreads();
  sA = (red[8] + red[9]) + (red[10] + red[11]);
  sB = (red[12] + red[13]) + (red[14] + red[15]);

  const float scA = 0.03125f / sA;  // post-softmax 1/sqrt(Dk)=1/32 folded in
  const float scB = 0.03125f / sB;
  f16x8 oA, oB;
#pragma unroll
  for (int j = 0; j < 8; ++j) {
    oA[j] = (_Float16)(eA[j] * scA);
    oB[j] = (_Float16)(eB[j] * scB);
  }
  ((f16x8*)prowA)[t] = oA;
  ((f16x8*)prowB)[t] = oB;
}

// ---------------------------------------------------------------------------
// Kernel 4: O[b] = P[b] @ V[b]  (Vt [v][s] -> B^T GEMM, K=2048), f32 out.
// 1-D grid, 128 blocks/batch: m=(r&7)+8*(r>>6), n=(r>>3)&7.
__global__ __launch_bounds__(256, 2) void pv_kernel(
    const _Float16* __restrict__ P, const _Float16* __restrict__ Vt,
    float* __restrict__ out) {
  __shared__ alignas(16) _Float16 As[BM * BK];
  __shared__ alignas(16) _Float16 Bs[BN * BK];
  f32x4 acc[4][4] = {};
  const int l = blockIdx.x;
  const int b = l >> 7;
  const int r7 = l & 127;
  const int m0 = ((r7 & 7) | ((r7 >> 6) << 3)) * BM;
  const int n0 = ((r7 >> 3) & 7) * BN;
  gemm_core(P + (size_t)b * SEQ * SEQ, SEQ,
            Vt + (size_t)b * DIM * SEQ, SEQ, SEQ, m0, n0, As, Bs, acc);
  float* ob = out + (size_t)b * SEQ * DIM;
  const int t = threadIdx.x, w = t >> 6, lrow = t & 15, quad = (t >> 4) & 3;
  const int wm = (w >> 1) << 6, wn = (w & 1) << 6;
#pragma unroll
  for (int ni = 0; ni < 4; ++ni) {
    const int col = n0 + wn + ni * 16 + lrow;
#pragma unroll
    for (int mi = 0; mi < 4; ++mi) {
#pragma unroll
      for (int r = 0; r < 4; ++r) {
        const int row = m0 + wm + mi * 16 + quad * 4 + r;
        ob[(size_t)row * DIM + col] = acc[mi][ni][r];
      }
    }
  }
}

// ---------------------------------------------------------------------------
extern "C" void kernel_launch(void* const* d_in, const int* in_sizes, int n_in,
                              void* d_out, int out_size, void* d_ws, size_t ws_size,
                              hipStream_t stream) {
  const float* x  = (const float*)d_in[0];
  const float* Wq = (const float*)d_in[1];
  const float* bq = (const float*)d_in[2];
  const float* Wk = (const float*)d_in[3];
  const float* bk = (const float*)d_in[4];
  const float* Wv = (const float*)d_in[5];
  const float* bv = (const float*)d_in[6];
  float* out = (float*)d_out;  // reference output dtype is float32

  char* ws = (char*)d_ws;
  _Float16* Qp  = (_Float16*)(ws);                 // 16 MB [8192][1024]
  _Float16* Kp  = (_Float16*)(ws + 16777216);      // 16 MB
  _Float16* Vt  = (_Float16*)(ws + 33554432);      // 16 MB [4][1024][2048]
  _Float16* Sc  = (_Float16*)(ws + 50331648);      // 32 MB [4][2048][2048] f16
  _Float16* P   = (_Float16*)(ws + 117440512);     // 32 MB [4][2048][2048] f16
  // xh + W hi planes alias the Sc region (dead once scores_kernel runs).
  _Float16* xh  = (_Float16*)(ws + 50331648);      // 16 MB [8192][1024]
  _Float16* Wqh = (_Float16*)(ws + 67108864);      //  2 MB (dead after qkv)
  _Float16* Wkh = (_Float16*)(ws + 69206016);      //  2 MB (dead after qkv)
  _Float16* Wvh = (_Float16*)(ws + 71303168);      //  2 MB (dead after qkv)
  // peak 150,994,944 B

  dim3 blk(256, 1, 1);
  split_all_kernel<<<dim3(MTOT + 3 * DIM), blk, 0, stream>>>(
      x, Wq, Wk, Wv, xh, Wqh, Wkh, Wvh);
  qkv_kernel<<<dim3(3 * 512), blk, 0, stream>>>(
      xh, Wqh, bq, Wkh, bk, Wvh, bv, Qp, Kp, Vt);
  scores_kernel<<<dim3(NBATCH * 256), blk, 0, stream>>>(Qp, Kp, Sc);
  softmax_kernel<<<dim3(MTOT / 2), blk, 0, stream>>>(Sc, P);
  pv_kernel<<<dim3(NBATCH * 128), blk, 0, stream>>>(P, Vt, out);
}